// Round 16
// baseline (6697.195 us; speedup 1.0000x reference)
//
#include <hip/hip_runtime.h>
#include <hip/hip_bf16.h>

// Problem constants
#define BB   128
#define SS   512
#define IND  512
#define HID  1024
#define NBLK 256     // 4 row-quarters (mi) x 64 column-groups (jg)
#define GRPBLK 64    // blocks per mi-group (independent sub-GRU)
#define NSTRIPE 8    // stripes per group (one 64B LLC line each)

typedef __attribute__((ext_vector_type(8))) short s8v;   // 8 x bf16
typedef __attribute__((ext_vector_type(4))) float f4v;   // MFMA accumulator
typedef unsigned long long u64;
typedef unsigned int u32;

__device__ __forceinline__ short f2bf(float f) {
    union { float f; u32 u; } v; v.f = f;
    u32 u = v.u + 0x7FFFu + ((v.u >> 16) & 1u);          // RNE
    return (short)(u >> 16);
}

// h ping-pong layout (bf16): as R8 (PROVEN).
//   bufA (ws): [wg=8][kk=32][kg=4][row 16][8 shorts]
//   bufB (out tail): group mi slice at mi*131072 + (wg&1)*32768 + rest
//
// R15 = R14 + two changes:
// 1) h prefetch via ONE asm volatile block of 32 global_load_dwordx4
//    (sc0 sc1 = system-coherent >= previous agent atomic loads): 32 "=&v"
//    early-clobber outputs force all 128 VGPRs live -> all loads in flight
//    across gi; s_waitcnt vmcnt(0) + sched_barrier(0) before gh (rule #18).
//    R8/R12/R14's VGPR=132 proved the allocator was batch-serializing the
//    loads inside gh (~8 exposed LLC round-trips/step).
// 2) weight LDS gate-major [g][kk][lane][16B] with 3 hoisted per-gate base
//    pointers so every ds_read offset fits the 16-bit immediate (R14's
//    [kk][g] layout overflowed at high kk -> extra addr VALU).

__global__ void __launch_bounds__(128, 1)
gru_persistent(const float* __restrict__ X,     // [B,S,IND]
               const float* __restrict__ Wih,   // [3H, IND]
               const float* __restrict__ Whh,   // [3H, HID]
               const float* __restrict__ bih,   // [3H]
               const float* __restrict__ bhh,   // [3H]
               float* __restrict__ out,         // [B,S,H] ++ [B,H]
               short* __restrict__ bufA,        // ws scratch (even t)
               short* __restrict__ bufB,        // d_out tail region (odd t)
               u64*   __restrict__ ctr)         // 4 groups x 8 stripes, 64B apart
{
    __shared__ __align__(16) short whh2[3 * 32 * 64 * 8]; // 98304 B
    __shared__ __align__(16) short wih2[3 * 16 * 64 * 8]; // 49152 B

    const int tid  = threadIdx.x;
    const int wave = tid >> 6;      // 0..1
    const int lane = tid & 63;
    const int blk  = blockIdx.x;
    const int mi   = blk >> 6;      // 0..3 row quarter == barrier group
    const int jg   = blk & 63;      // column group

    // ---- stage weight slices to LDS as bf16, gate-major fragment layout ----
    // element (gate g, out-col n_, k) -> w2[((g*NKK + k/32)*64 + ((k>>3)&3)*16 + n_)*8 + (k&7)]
    for (int idx = tid; idx < 48 * (HID / 4); idx += 128) {
        int s = idx >> 8, k4 = idx & 255;                 // s = g*16+n_
        int g = s >> 4, n_ = s & 15;
        int grow = g * HID + jg * 16 + n_;
        float4 v = *(const float4*)(Whh + (size_t)grow * HID + k4 * 4);
        int k  = k4 * 4;
        int kk = k >> 5, kg_ = (k >> 3) & 3, e0 = k & 7;
        short* d = &whh2[(((g * 32 + kk) * 64) + (kg_ * 16 + n_)) * 8 + e0];
        d[0] = f2bf(v.x); d[1] = f2bf(v.y); d[2] = f2bf(v.z); d[3] = f2bf(v.w);
    }
    for (int idx = tid; idx < 48 * (IND / 4); idx += 128) {
        int s = idx >> 7, k4 = idx & 127;
        int g = s >> 4, n_ = s & 15;
        int grow = g * HID + jg * 16 + n_;
        float4 v = *(const float4*)(Wih + (size_t)grow * IND + k4 * 4);
        int k  = k4 * 4;
        int kk = k >> 5, kg_ = (k >> 3) & 3, e0 = k & 7;
        short* d = &wih2[(((g * 16 + kk) * 64) + (kg_ * 16 + n_)) * 8 + e0];
        d[0] = f2bf(v.x); d[1] = f2bf(v.y); d[2] = f2bf(v.z); d[3] = f2bf(v.w);
    }

    // per-gate LDS base pointers (offsets then fit 16-bit ds_read immediates)
    const short* wihr = wih2;
    const short* wihz = wih2 + 16 * 64 * 8;
    const short* wihn = wih2 + 2 * 16 * 64 * 8;
    const short* whhr = whh2;
    const short* whhz = whh2 + 32 * 64 * 8;
    const short* whhn = whh2 + 2 * 32 * 64 * 8;

    const int n  = lane & 15;
    const int kg = lane >> 4;
    const int j  = jg * 16 + n;
    const float bir = bih[j], biz = bih[HID + j], bin_ = bih[2 * HID + j];
    const float bhr = bhh[j], bhz = bhh[HID + j], bhn  = bhh[2 * HID + j];

    const int rowbase = mi * 32 + wave * 16;
    const int wg      = mi * 2 + wave;          // row-group = rowbase/16

    // writer byte offsets (even lanes store packed u32 covering cols j, j+1)
    const int wkk = j >> 5, wkg = (j >> 3) & 3;
    const u32 rest   = (u32)wkk * 1024u + (u32)wkg * 256u
                     + (u32)kg * 64u + ((u32)(n & 7) << 1);
    const u32 wbyteA = (u32)wg * 32768u + rest;
    const u32 wbyteB = (u32)mi * 131072u + (u32)(wg & 1) * 32768u + rest;

    // h reader slice bases (per-lane 16B at lane*16, fragment kk at +kk*1024)
    const char* hslabA = (const char*)bufA + (size_t)wg * 32768;
    const char* hslabB = (const char*)bufB + (size_t)mi * 131072
                       + (size_t)(wg & 1) * 32768;

    float hkeep[4] = {0.f, 0.f, 0.f, 0.f};      // this lane's own h elements

    __syncthreads();

    for (int t = 0; t < SS; ++t) {
        f4v acc_r  = {0.f,0.f,0.f,0.f};
        f4v acc_z  = {0.f,0.f,0.f,0.f};
        f4v acc_in = {0.f,0.f,0.f,0.f};
        f4v acc_hn = {0.f,0.f,0.f,0.f};
        s8v areg[32];

        // ---- h_{t-1}: ALL 32 x 16B loads issued in one asm block.
        // Early-clobber outputs force 128 VGPRs live -> no re-batching; the
        // single LLC round-trip hides under gi. Bytes/addresses identical to
        // the previous __hip_atomic_load pairs -> bit-identical numerics.
        if (t > 0) {
            const char* hbase = (t & 1) ? hslabA : hslabB;
            u64 ha0 = (u64)hbase + (u32)(lane * 16);
            u64 ha1 = ha0 + 4096,  ha2 = ha0 + 8192,  ha3 = ha0 + 12288;
            u64 ha4 = ha0 + 16384, ha5 = ha0 + 20480, ha6 = ha0 + 24576;
            u64 ha7 = ha0 + 28672;
            asm volatile(
                "global_load_dwordx4 %0,  %32, off sc0 sc1\n\t"
                "global_load_dwordx4 %1,  %32, off offset:1024 sc0 sc1\n\t"
                "global_load_dwordx4 %2,  %32, off offset:2048 sc0 sc1\n\t"
                "global_load_dwordx4 %3,  %32, off offset:3072 sc0 sc1\n\t"
                "global_load_dwordx4 %4,  %33, off sc0 sc1\n\t"
                "global_load_dwordx4 %5,  %33, off offset:1024 sc0 sc1\n\t"
                "global_load_dwordx4 %6,  %33, off offset:2048 sc0 sc1\n\t"
                "global_load_dwordx4 %7,  %33, off offset:3072 sc0 sc1\n\t"
                "global_load_dwordx4 %8,  %34, off sc0 sc1\n\t"
                "global_load_dwordx4 %9,  %34, off offset:1024 sc0 sc1\n\t"
                "global_load_dwordx4 %10, %34, off offset:2048 sc0 sc1\n\t"
                "global_load_dwordx4 %11, %34, off offset:3072 sc0 sc1\n\t"
                "global_load_dwordx4 %12, %35, off sc0 sc1\n\t"
                "global_load_dwordx4 %13, %35, off offset:1024 sc0 sc1\n\t"
                "global_load_dwordx4 %14, %35, off offset:2048 sc0 sc1\n\t"
                "global_load_dwordx4 %15, %35, off offset:3072 sc0 sc1\n\t"
                "global_load_dwordx4 %16, %36, off sc0 sc1\n\t"
                "global_load_dwordx4 %17, %36, off offset:1024 sc0 sc1\n\t"
                "global_load_dwordx4 %18, %36, off offset:2048 sc0 sc1\n\t"
                "global_load_dwordx4 %19, %36, off offset:3072 sc0 sc1\n\t"
                "global_load_dwordx4 %20, %37, off sc0 sc1\n\t"
                "global_load_dwordx4 %21, %37, off offset:1024 sc0 sc1\n\t"
                "global_load_dwordx4 %22, %37, off offset:2048 sc0 sc1\n\t"
                "global_load_dwordx4 %23, %37, off offset:3072 sc0 sc1\n\t"
                "global_load_dwordx4 %24, %38, off sc0 sc1\n\t"
                "global_load_dwordx4 %25, %38, off offset:1024 sc0 sc1\n\t"
                "global_load_dwordx4 %26, %38, off offset:2048 sc0 sc1\n\t"
                "global_load_dwordx4 %27, %38, off offset:3072 sc0 sc1\n\t"
                "global_load_dwordx4 %28, %39, off sc0 sc1\n\t"
                "global_load_dwordx4 %29, %39, off offset:1024 sc0 sc1\n\t"
                "global_load_dwordx4 %30, %39, off offset:2048 sc0 sc1\n\t"
                "global_load_dwordx4 %31, %39, off offset:3072 sc0 sc1"
                : "=&v"(areg[0]),  "=&v"(areg[1]),  "=&v"(areg[2]),  "=&v"(areg[3]),
                  "=&v"(areg[4]),  "=&v"(areg[5]),  "=&v"(areg[6]),  "=&v"(areg[7]),
                  "=&v"(areg[8]),  "=&v"(areg[9]),  "=&v"(areg[10]), "=&v"(areg[11]),
                  "=&v"(areg[12]), "=&v"(areg[13]), "=&v"(areg[14]), "=&v"(areg[15]),
                  "=&v"(areg[16]), "=&v"(areg[17]), "=&v"(areg[18]), "=&v"(areg[19]),
                  "=&v"(areg[20]), "=&v"(areg[21]), "=&v"(areg[22]), "=&v"(areg[23]),
                  "=&v"(areg[24]), "=&v"(areg[25]), "=&v"(areg[26]), "=&v"(areg[27]),
                  "=&v"(areg[28]), "=&v"(areg[29]), "=&v"(areg[30]), "=&v"(areg[31])
                : "v"(ha0), "v"(ha1), "v"(ha2), "v"(ha3),
                  "v"(ha4), "v"(ha5), "v"(ha6), "v"(ha7)
                : "memory");
        }

        // ---- gi: X[:,t,:] @ Wih_slice^T (K=512) — hides the h-load RT ----
        {
            const float* xrow = X + ((size_t)(rowbase + n) * SS + t) * IND;
            #pragma unroll 4
            for (int kk = 0; kk < IND / 32; ++kk) {
                const int k0 = kk * 32 + kg * 8;
                const float4* px = (const float4*)(xrow + k0);
                float4 x0 = px[0], x1 = px[1];
                s8v a;
                a[0]=f2bf(x0.x); a[1]=f2bf(x0.y); a[2]=f2bf(x0.z); a[3]=f2bf(x0.w);
                a[4]=f2bf(x1.x); a[5]=f2bf(x1.y); a[6]=f2bf(x1.z); a[7]=f2bf(x1.w);
                s8v br = *(const s8v*)&wihr[((kk << 6) | lane) << 3];
                s8v bz = *(const s8v*)&wihz[((kk << 6) | lane) << 3];
                s8v bn = *(const s8v*)&wihn[((kk << 6) | lane) << 3];
                acc_r  = __builtin_amdgcn_mfma_f32_16x16x32_bf16(a, br, acc_r,  0,0,0);
                acc_z  = __builtin_amdgcn_mfma_f32_16x16x32_bf16(a, bz, acc_z,  0,0,0);
                acc_in = __builtin_amdgcn_mfma_f32_16x16x32_bf16(a, bn, acc_in, 0,0,0);
            }
        }

        // ---- gh: wait for the asm loads (compiler can't track them), then MFMA
        if (t > 0) {
            asm volatile("s_waitcnt vmcnt(0)" ::: "memory");
            __builtin_amdgcn_sched_barrier(0);   // rule #18: pin MFMAs below the wait
            #pragma unroll
            for (int kk = 0; kk < 32; ++kk) {
                s8v br = *(const s8v*)&whhr[((kk << 6) | lane) << 3];
                s8v bz = *(const s8v*)&whhz[((kk << 6) | lane) << 3];
                s8v bn = *(const s8v*)&whhn[((kk << 6) | lane) << 3];
                acc_r  = __builtin_amdgcn_mfma_f32_16x16x32_bf16(areg[kk], br, acc_r,  0,0,0);
                acc_z  = __builtin_amdgcn_mfma_f32_16x16x32_bf16(areg[kk], bz, acc_z,  0,0,0);
                acc_hn = __builtin_amdgcn_mfma_f32_16x16x32_bf16(areg[kk], bn, acc_hn, 0,0,0);
            }
        }

        // ---- gates + state update; h kept in regs (R8 verbatim) ----
        u32 packv[4];
        #pragma unroll
        for (int r = 0; r < 4; ++r) {
            const int b = rowbase + kg * 4 + r;
            float gr = acc_r[r] + bir + bhr;
            float gz = acc_z[r] + biz + bhz;
            float rr = 1.f / (1.f + __expf(-gr));
            float zz = 1.f / (1.f + __expf(-gz));
            float hn = acc_hn[r] + bhn;                       // t=0: == bhn
            float na = acc_in[r] + bin_ + rr * hn;
            float e2 = __expf(2.f * na);
            float nn = (e2 - 1.f) / (e2 + 1.f);
            float hnew = (1.f - zz) * nn + zz * hkeep[r];
            hkeep[r] = hnew;
            out[(size_t)b * (SS * HID) + (size_t)t * HID + j] = hnew;
            if (t == SS - 1)
                out[(size_t)BB * SS * HID + (size_t)b * HID + j] = hnew;
            u32 hb16  = (u32)(unsigned short)f2bf(hnew);
            u32 other = (u32)__shfl_xor((int)hb16, 1);
            packv[r] = hb16 | (other << 16);                  // cols j (lo), j+1 (hi)
        }

        if (t < SS - 1) {
            if (!(n & 1)) {
                char* base = (t & 1) ? ((char*)bufB + wbyteB) : ((char*)bufA + wbyteA);
                #pragma unroll
                for (int r = 0; r < 4; ++r)
                    __hip_atomic_store((u32*)(base + r * 16), packv[r],
                                       __ATOMIC_RELAXED, __HIP_MEMORY_SCOPE_AGENT);
            }
            // ---- per-mi-group barrier (64 blocks), striped fan-in + poll.
            // __syncthreads drains vmcnt(0) -> all h stores at LLC before arrive.
            // NOTHING between arrive and poll (R3/R4/R13 rule).
            __syncthreads();
            if (tid == 0) {
                __hip_atomic_fetch_add(&ctr[(mi * NSTRIPE + (blk & 7)) * 8], 1ull,
                                       __ATOMIC_RELAXED, __HIP_MEMORY_SCOPE_AGENT);
                const u64 target = (u64)GRPBLK * (u64)(t + 1);
                for (;;) {
                    u64 s = 0;
                    #pragma unroll
                    for (int i = 0; i < NSTRIPE; ++i)
                        s += __hip_atomic_load(&ctr[(mi * NSTRIPE + i) * 8],
                                               __ATOMIC_RELAXED,
                                               __HIP_MEMORY_SCOPE_AGENT);
                    if (s >= target) break;
                    __builtin_amdgcn_s_sleep(1);
                }
            }
            __syncthreads();
        }
    }
}

extern "C" void kernel_launch(void* const* d_in, const int* in_sizes, int n_in,
                              void* d_out, int out_size, void* d_ws, size_t ws_size,
                              hipStream_t stream) {
    const float* X   = (const float*)d_in[0];
    const float* Wih = (const float*)d_in[1];
    const float* Whh = (const float*)d_in[2];
    const float* bih = (const float*)d_in[3];
    const float* bhh = (const float*)d_in[4];
    float* out = (float*)d_out;

    u64*   ctr  = (u64*)d_ws;                         // 4x8 stripes on 64B stride
    short* bufA = (short*)((char*)d_ws + 4096);       // 256 KB (even-t h)
    // odd-t h: per-group 64 KB slices inside each group's OWN h_last rows
    // (tail bytes [mi*128KB, +64KB)); overwritten group-locally at t=SS-1
    // after the group's t=SS-2 barrier.
    short* bufB = (short*)(out + (size_t)BB * SS * HID);

    hipMemsetAsync(d_ws, 0, 4096, stream);            // zero barrier stripes

    void* args[] = { (void*)&X, (void*)&Wih, (void*)&Whh, (void*)&bih,
                     (void*)&bhh, (void*)&out, (void*)&bufA, (void*)&bufB,
                     (void*)&ctr };
    hipLaunchCooperativeKernel((const void*)gru_persistent,
                               dim3(NBLK), dim3(128), args, 0, stream);
}

// Round 17
// 3794.675 us; speedup vs baseline: 1.7649x; 1.7649x over previous
//
#include <hip/hip_runtime.h>
#include <hip/hip_bf16.h>

// Problem constants
#define BB   128
#define SS   512
#define IND  512
#define HID  1024
#define NBLK 256     // 4 row-quarters (mi) x 64 column-groups (jg)
#define GRPBLK 64    // blocks per mi-group (independent sub-GRU)
#define NSTRIPE 8    // stripes per group (one 64B LLC line each)

#define WHH_LD (HID + 8)   // LDS row pad
#define WIH_LD (IND + 8)

typedef __attribute__((ext_vector_type(8))) short s8v;   // 8 x bf16
typedef __attribute__((ext_vector_type(4))) float f4v;   // MFMA accumulator
typedef unsigned long long u64;
typedef unsigned int u32;

__device__ __forceinline__ short f2bf(float f) {
    union { float f; u32 u; } v; v.f = f;
    u32 u = v.u + 0x7FFFu + ((v.u >> 16) & 1u);          // RNE
    return (short)(u >> 16);
}

// h ping-pong layout (bf16): as R8 (PROVEN).
//   bufA (ws): [wg=8][kk=32][kg=4][row 16][8 shorts]
//   bufB (out tail): group mi slice at mi*131072 + (wg&1)*32768 + rest
//
// R16 = R8 + two value-identical changes:
// 1) gh software-pipelined in 4 chunks of 8 kk: chunk c+1's agent-scope
//    atomic loads are ISSUED (pinned by sched_barrier(0), a hard fence)
//    before chunk c's MFMAs consume -> compiler emits counted vmcnt waits,
//    LLC latency overlaps MFMA instead of serializing ~4x (R8's VGPR=132
//    proved batch-serialized loads).
// 2) h stores packed to u64 (2 shfl_xor gather; lanes n%4==0 store 8B)
//    -> half the LLC write transactions -> shorter pre-arrive drain.
// MFMA order and all stored bytes identical to R8 -> bit-identical output.

__global__ void __launch_bounds__(128, 1)
gru_persistent(const float* __restrict__ X,     // [B,S,IND]
               const float* __restrict__ Wih,   // [3H, IND]
               const float* __restrict__ Whh,   // [3H, HID]
               const float* __restrict__ bih,   // [3H]
               const float* __restrict__ bhh,   // [3H]
               float* __restrict__ out,         // [B,S,H] ++ [B,H]
               short* __restrict__ bufA,        // ws scratch (even t)
               short* __restrict__ bufB,        // d_out tail region (odd t)
               u64*   __restrict__ ctr)         // 4 groups x 8 stripes, 64B apart
{
    __shared__ __align__(16) short whh_lds[48 * WHH_LD];   // 99072 B
    __shared__ __align__(16) short wih_lds[48 * WIH_LD];   // 49920 B

    const int tid  = threadIdx.x;
    const int wave = tid >> 6;      // 0..1
    const int lane = tid & 63;
    const int blk  = blockIdx.x;
    const int mi   = blk >> 6;      // 0..3 row quarter == barrier group
    const int jg   = blk & 63;      // column group

    // ---- stage weight slices to LDS as bf16 (once; R8 layout) ----
    for (int idx = tid; idx < 48 * (HID / 4); idx += 128) {
        int s = idx / (HID / 4), k4 = idx % (HID / 4);
        int grow = (s >> 4) * HID + jg * 16 + (s & 15);
        float4 v = *(const float4*)(Whh + (size_t)grow * HID + k4 * 4);
        short* d = &whh_lds[s * WHH_LD + k4 * 4];
        d[0] = f2bf(v.x); d[1] = f2bf(v.y); d[2] = f2bf(v.z); d[3] = f2bf(v.w);
    }
    for (int idx = tid; idx < 48 * (IND / 4); idx += 128) {
        int s = idx / (IND / 4), k4 = idx % (IND / 4);
        int grow = (s >> 4) * HID + jg * 16 + (s & 15);
        float4 v = *(const float4*)(Wih + (size_t)grow * IND + k4 * 4);
        short* d = &wih_lds[s * WIH_LD + k4 * 4];
        d[0] = f2bf(v.x); d[1] = f2bf(v.y); d[2] = f2bf(v.z); d[3] = f2bf(v.w);
    }

    const int n  = lane & 15;
    const int kg = lane >> 4;
    const int j  = jg * 16 + n;
    const float bir = bih[j], biz = bih[HID + j], bin_ = bih[2 * HID + j];
    const float bhr = bhh[j], bhz = bhh[HID + j], bhn  = bhh[2 * HID + j];

    const int rowbase = mi * 32 + wave * 16;
    const int wg      = mi * 2 + wave;          // row-group = rowbase/16

    // writer byte offsets (lanes n%4==0 store packed u64 = cols j..j+3)
    const int wkk = j >> 5, wkg = (j >> 3) & 3;
    const u32 rest   = (u32)wkk * 1024u + (u32)wkg * 256u
                     + (u32)kg * 64u + ((u32)(n & 7) << 1);
    const u32 wbyteA = (u32)wg * 32768u + rest;
    const u32 wbyteB = (u32)mi * 131072u + (u32)(wg & 1) * 32768u + rest;

    // reader u64 offsets (lane-contiguous 16B per lane)
    const u64* hbA = (const u64*)bufA + (size_t)wg * 4096 + lane * 2;
    const u64* hbB = (const u64*)bufB + (size_t)mi * 16384
                   + (size_t)(wg & 1) * 4096 + lane * 2;

    float hkeep[4] = {0.f, 0.f, 0.f, 0.f};      // this lane's own h elements

    __syncthreads();

    for (int t = 0; t < SS; ++t) {
        f4v acc_r  = {0.f,0.f,0.f,0.f};
        f4v acc_z  = {0.f,0.f,0.f,0.f};
        f4v acc_in = {0.f,0.f,0.f,0.f};
        f4v acc_hn = {0.f,0.f,0.f,0.f};

        // ---- gi: X[:,t,:] @ Wih_slice^T (K=512), normal cached loads ----
        {
            const float* xrow = X + ((size_t)(rowbase + n) * SS + t) * IND;
            #pragma unroll 4
            for (int kk = 0; kk < IND / 32; ++kk) {
                const int k0 = kk * 32 + kg * 8;
                const float4* px = (const float4*)(xrow + k0);
                float4 x0 = px[0], x1 = px[1];
                s8v a;
                a[0]=f2bf(x0.x); a[1]=f2bf(x0.y); a[2]=f2bf(x0.z); a[3]=f2bf(x0.w);
                a[4]=f2bf(x1.x); a[5]=f2bf(x1.y); a[6]=f2bf(x1.z); a[7]=f2bf(x1.w);
                s8v br = *(const s8v*)&wih_lds[(0 * 16 + n) * WIH_LD + k0];
                s8v bz = *(const s8v*)&wih_lds[(1 * 16 + n) * WIH_LD + k0];
                s8v bn = *(const s8v*)&wih_lds[(2 * 16 + n) * WIH_LD + k0];
                acc_r  = __builtin_amdgcn_mfma_f32_16x16x32_bf16(a, br, acc_r,  0,0,0);
                acc_z  = __builtin_amdgcn_mfma_f32_16x16x32_bf16(a, bz, acc_z,  0,0,0);
                acc_in = __builtin_amdgcn_mfma_f32_16x16x32_bf16(a, bn, acc_in, 0,0,0);
            }
        }

        // ---- gh: software-pipelined in 4 chunks of 8 kk.
        // Chunk c+1 loads ISSUE (pinned) before chunk c MFMAs; compiler
        // inserts counted vmcnt -> LLC RT overlaps MFMA. Same addresses,
        // same kk order as R8 -> bit-identical.
        if (t > 0) {
            const u64* hb = (t & 1) ? hbA : hbB;              // h_{t-1}
            s8v areg[32];
            #pragma unroll
            for (int q = 0; q < 8; ++q) {                     // chunk 0
                u64 lo = __hip_atomic_load(hb + q * 128,
                                           __ATOMIC_RELAXED, __HIP_MEMORY_SCOPE_AGENT);
                u64 hi = __hip_atomic_load(hb + q * 128 + 1,
                                           __ATOMIC_RELAXED, __HIP_MEMORY_SCOPE_AGENT);
                union { u64 qq[2]; s8v v; } u; u.qq[0] = lo; u.qq[1] = hi;
                areg[q] = u.v;
            }
            __builtin_amdgcn_sched_barrier(0);
            #pragma unroll
            for (int c = 0; c < 4; ++c) {
                if (c < 3) {
                    #pragma unroll
                    for (int q = 0; q < 8; ++q) {             // issue chunk c+1
                        const int kk = (c + 1) * 8 + q;
                        u64 lo = __hip_atomic_load(hb + kk * 128,
                                                   __ATOMIC_RELAXED, __HIP_MEMORY_SCOPE_AGENT);
                        u64 hi = __hip_atomic_load(hb + kk * 128 + 1,
                                                   __ATOMIC_RELAXED, __HIP_MEMORY_SCOPE_AGENT);
                        union { u64 qq[2]; s8v v; } u; u.qq[0] = lo; u.qq[1] = hi;
                        areg[kk] = u.v;
                    }
                }
                __builtin_amdgcn_sched_barrier(0);
                #pragma unroll
                for (int q = 0; q < 8; ++q) {                 // consume chunk c
                    const int kk = c * 8 + q;
                    const int k0 = kk * 32 + kg * 8;
                    s8v br = *(const s8v*)&whh_lds[(0 * 16 + n) * WHH_LD + k0];
                    s8v bz = *(const s8v*)&whh_lds[(1 * 16 + n) * WHH_LD + k0];
                    s8v bn = *(const s8v*)&whh_lds[(2 * 16 + n) * WHH_LD + k0];
                    acc_r  = __builtin_amdgcn_mfma_f32_16x16x32_bf16(areg[kk], br, acc_r,  0,0,0);
                    acc_z  = __builtin_amdgcn_mfma_f32_16x16x32_bf16(areg[kk], bz, acc_z,  0,0,0);
                    acc_hn = __builtin_amdgcn_mfma_f32_16x16x32_bf16(areg[kk], bn, acc_hn, 0,0,0);
                }
                __builtin_amdgcn_sched_barrier(0);
            }
        }

        // ---- gates + state update (R8 epilogue; u64-packed h stores) ----
        u64 pack2[4];
        float hnew4[4];
        #pragma unroll
        for (int r = 0; r < 4; ++r) {
            float gr = acc_r[r] + bir + bhr;
            float gz = acc_z[r] + biz + bhz;
            float rr = 1.f / (1.f + __expf(-gr));
            float zz = 1.f / (1.f + __expf(-gz));
            float hn = acc_hn[r] + bhn;                       // t=0: == bhn
            float na = acc_in[r] + bin_ + rr * hn;
            float e2 = __expf(2.f * na);
            float nn = (e2 - 1.f) / (e2 + 1.f);
            float hnew = (1.f - zz) * nn + zz * hkeep[r];
            hkeep[r] = hnew;
            hnew4[r] = hnew;
            u32 hb16 = (u32)(unsigned short)f2bf(hnew);
            u32 p = hb16 | ((u32)__shfl_xor((int)hb16, 1) << 16); // cols n,n+1 (even n)
            u32 q = (u32)__shfl_xor((int)p, 2);                   // cols n+2,n+3 (n%4==0)
            pack2[r] = (u64)p | ((u64)q << 32);                   // cols j..j+3
        }
        #pragma unroll
        for (int r = 0; r < 4; ++r) {
            const int b = rowbase + kg * 4 + r;
            out[(size_t)b * (SS * HID) + (size_t)t * HID + j] = hnew4[r];
            if (t == SS - 1)
                out[(size_t)BB * SS * HID + (size_t)b * HID + j] = hnew4[r];
        }

        if (t < SS - 1) {
            if (!(n & 3)) {
                char* base = (t & 1) ? ((char*)bufB + wbyteB) : ((char*)bufA + wbyteA);
                #pragma unroll
                for (int r = 0; r < 4; ++r)
                    __hip_atomic_store((u64*)(base + r * 16), pack2[r],
                                       __ATOMIC_RELAXED, __HIP_MEMORY_SCOPE_AGENT);
            }
            // ---- per-mi-group barrier (64 blocks), striped fan-in + poll.
            // __syncthreads drains vmcnt(0) -> all h stores at LLC before arrive.
            // NOTHING between arrive and poll (R3/R4/R13 rule).
            __syncthreads();
            if (tid == 0) {
                __hip_atomic_fetch_add(&ctr[(mi * NSTRIPE + (blk & 7)) * 8], 1ull,
                                       __ATOMIC_RELAXED, __HIP_MEMORY_SCOPE_AGENT);
                const u64 target = (u64)GRPBLK * (u64)(t + 1);
                for (;;) {
                    u64 s = 0;
                    #pragma unroll
                    for (int i = 0; i < NSTRIPE; ++i)
                        s += __hip_atomic_load(&ctr[(mi * NSTRIPE + i) * 8],
                                               __ATOMIC_RELAXED,
                                               __HIP_MEMORY_SCOPE_AGENT);
                    if (s >= target) break;
                    __builtin_amdgcn_s_sleep(1);
                }
            }
            __syncthreads();
        }
    }
}

extern "C" void kernel_launch(void* const* d_in, const int* in_sizes, int n_in,
                              void* d_out, int out_size, void* d_ws, size_t ws_size,
                              hipStream_t stream) {
    const float* X   = (const float*)d_in[0];
    const float* Wih = (const float*)d_in[1];
    const float* Whh = (const float*)d_in[2];
    const float* bih = (const float*)d_in[3];
    const float* bhh = (const float*)d_in[4];
    float* out = (float*)d_out;

    u64*   ctr  = (u64*)d_ws;                         // 4x8 stripes on 64B stride
    short* bufA = (short*)((char*)d_ws + 4096);       // 256 KB (even-t h)
    // odd-t h: per-group 64 KB slices inside each group's OWN h_last rows
    // (tail bytes [mi*128KB, +64KB)); overwritten group-locally at t=SS-1
    // after the group's t=SS-2 barrier.
    short* bufB = (short*)(out + (size_t)BB * SS * HID);

    hipMemsetAsync(d_ws, 0, 4096, stream);            // zero barrier stripes

    void* args[] = { (void*)&X, (void*)&Wih, (void*)&Whh, (void*)&bih,
                     (void*)&bhh, (void*)&out, (void*)&bufA, (void*)&bufB,
                     (void*)&ctr };
    hipLaunchCooperativeKernel((const void*)gru_persistent,
                               dim3(NBLK), dim3(128), args, 0, stream);
}